// Round 1
// baseline (134.356 us; speedup 1.0000x reference)
//
#include <hip/hip_runtime.h>

// CenterLoss: loss = sum_i clamp(||pred_i||^2 + ||c_{t_i}||^2 - 2 pred_i.c_{t_i}, 1e-12, 1e12)
//             + BATCH*(NUM_CLASSES-1)*1e-12
// pred: [16384, 1024] f32, centers: [10000, 1024] f32, target: [16384] int
// Memory-bound: ~64 MiB pred stream + <=40 MiB centers gather -> ~17 us floor.

constexpr int BATCH = 16384;
constexpr int FEAT = 1024;
constexpr int NUM_CLASSES = 10000;

__global__ void cl_init(float* __restrict__ out) {
    // masked-out entries contribute exactly BATCH*(NUM_CLASSES-1)*1e-12
    out[0] = (float)((double)BATCH * (double)(NUM_CLASSES - 1) * 1e-12);
}

__global__ __launch_bounds__(256) void cl_main(const float* __restrict__ pred,
                                               const float* __restrict__ centers,
                                               const int* __restrict__ target,
                                               float* __restrict__ out) {
    const int lane  = (int)(threadIdx.x & 63u);
    const int wave  = (int)(threadIdx.x >> 6);
    const int wpb   = (int)(blockDim.x >> 6);        // waves per block = 4
    const int gwave = (int)blockIdx.x * wpb + wave;
    const int nwaves = (int)gridDim.x * wpb;

    float local = 0.0f;  // only lane 0 of each wave accumulates

    for (int row = gwave; row < BATCH; row += nwaves) {
        const int t = target[row];  // wave-uniform broadcast load
        const float4* p = reinterpret_cast<const float4*>(pred    + (size_t)row * FEAT) + lane;
        const float4* c = reinterpret_cast<const float4*>(centers + (size_t)t   * FEAT) + lane;

        // 1024 floats = 256 float4 per row; 64 lanes x 4 float4 each, coalesced.
        float s = 0.0f;
#pragma unroll
        for (int j = 0; j < 4; ++j) {
            const float4 pv = p[64 * j];
            const float4 cv = c[64 * j];
            s += pv.x * pv.x + pv.y * pv.y + pv.z * pv.z + pv.w * pv.w;
            s += cv.x * cv.x + cv.y * cv.y + cv.z * cv.z + cv.w * cv.w;
            s -= 2.0f * (pv.x * cv.x + pv.y * cv.y + pv.z * cv.z + pv.w * cv.w);
        }

        // 64-lane butterfly reduction
#pragma unroll
        for (int off = 32; off > 0; off >>= 1)
            s += __shfl_xor(s, off, 64);

        if (lane == 0) {
            s = fminf(fmaxf(s, 1e-12f), 1e12f);  // clamp applies to the full distance
            local += s;
        }
    }

    __shared__ float red[8];
    if (lane == 0) red[wave] = local;
    __syncthreads();
    if (threadIdx.x == 0) {
        float b = 0.0f;
        for (int w = 0; w < wpb; ++w) b += red[w];
        atomicAdd(out, b);  // device-scope by default; one per block (2048 total)
    }
}

extern "C" void kernel_launch(void* const* d_in, const int* in_sizes, int n_in,
                              void* d_out, int out_size, void* d_ws, size_t ws_size,
                              hipStream_t stream) {
    const float* pred    = (const float*)d_in[0];
    const float* centers = (const float*)d_in[1];
    const int*   target  = (const int*)d_in[2];
    float*       out     = (float*)d_out;

    cl_init<<<1, 1, 0, stream>>>(out);
    // 2048 blocks x 256 threads = 8192 waves -> 2 rows per wave (grid-stride).
    // 2048 blocks = 8 blocks/CU on 256 CUs: full occupancy.
    cl_main<<<2048, 256, 0, stream>>>(pred, centers, target, out);
}